// Round 2
// baseline (944.606 us; speedup 1.0000x reference)
//
#include <hip/hip_runtime.h>
#include <hip/hip_fp16.h>

#define N_NODES 100000
#define IN_DIM 256
#define OUT_DIM 64
#define NT 782                 // dst tiles of 128 nodes
#define NB 256                 // binning blocks
#define SCHUNK 4096            // scan chunk: 256 threads * 16
#define SB ((NT * NB + SCHUNK - 1) / SCHUNK)   // 49 scan chunks
#define SCAN_M (NT * NB)       // 200192

typedef _Float16 half8 __attribute__((ext_vector_type(8)));
typedef float f32x4 __attribute__((ext_vector_type(4)));

// ---------------- pass 1: per-block LDS histogram of dst>>7; zero deg_out ----------------
__global__ __launch_bounds__(256) void count_kernel(const int* __restrict__ dst,
                                                    int* __restrict__ CD,
                                                    int* __restrict__ deg_out,
                                                    int E, int chunk) {
    __shared__ int hd[NT];
    const int t = threadIdx.x, blk = blockIdx.x;
    for (int i = t; i < NT; i += 256) hd[i] = 0;
    // zero deg_out (scatter_kernel atomically builds it next pass)
    for (int i = blk * 256 + t; i < N_NODES; i += NB * 256) deg_out[i] = 0;
    __syncthreads();
    const int lo = blk * chunk;
    int hi = lo + chunk; if (hi > E) hi = E;
    for (int i = lo + t; i < hi; i += 256)
        atomicAdd(&hd[dst[i] >> 7], 1);
    __syncthreads();
    for (int i = t; i < NT; i += 256)
        CD[i * NB + blk] = hd[i];
}

// ---------------- pass 2: chunk-local exclusive scan of CD (in place) + chunk totals ----------------
__global__ __launch_bounds__(256) void scan_blocks_kernel(int* __restrict__ CD, int* __restrict__ BS) {
    const int cid = blockIdx.x;
    const int t = threadIdx.x;
    const int base = cid * SCHUNK + t * 16;
    int pre[16];
    int s = 0;
#pragma unroll
    for (int r = 0; r < 16; ++r) {
        int v = (base + r < SCAN_M) ? CD[base + r] : 0;
        pre[r] = s; s += v;
    }
    const int lane = t & 63;
    int incl = s;
#pragma unroll
    for (int off = 1; off < 64; off <<= 1) {
        int y = __shfl_up(incl, off);
        if (lane >= off) incl += y;
    }
    int wave_excl = incl - s;
    __shared__ int wtot[4];
    if (lane == 63) wtot[t >> 6] = incl;
    __syncthreads();
    int woff = 0;
    for (int w = 0; w < (t >> 6); ++w) woff += wtot[w];
    int bexcl = woff + wave_excl;
#pragma unroll
    for (int r = 0; r < 16; ++r)
        if (base + r < SCAN_M) CD[base + r] = bexcl + pre[r];
    if (t == 0) BS[cid] = wtot[0] + wtot[1] + wtot[2] + wtot[3];
}

// ---------------- pass 3: deterministic scatter into dst-binned records + deg_out atomics ----------------
// record = (src << 7) | (dst & 127). The 49 chunk totals are scanned in-LDS by wave 0
// (replaces the old scan_sums launch).
__global__ __launch_bounds__(256) void scatter_kernel(const int* __restrict__ src,
                                                      const int* __restrict__ dst,
                                                      const int* __restrict__ CD,
                                                      const int* __restrict__ BS,
                                                      int* __restrict__ binnedD,
                                                      int* __restrict__ deg_out,
                                                      int E, int chunk) {
    __shared__ int curD[NT];
    __shared__ int sBS[64];
    const int t = threadIdx.x, blk = blockIdx.x;
    if (t < 64) {
        int v = (t < SB) ? BS[t] : 0;
        int incl = v;
#pragma unroll
        for (int off = 1; off < 64; off <<= 1) {
            int y = __shfl_up(incl, off);
            if (t >= off) incl += y;
        }
        sBS[t] = incl - v;
    }
    __syncthreads();
    for (int i = t; i < NT; i += 256) {
        int idx = i * NB + blk;
        curD[i] = CD[idx] + sBS[idx >> 12];
    }
    __syncthreads();
    const int lo = blk * chunk;
    int hi = lo + chunk; if (hi > E) hi = E;
    for (int i = lo + t; i < hi; i += 256) {
        int s = src[i], d = dst[i];
        atomicAdd(&deg_out[s], 1);
        int p = atomicAdd(&curD[d >> 7], 1);
        binnedD[p] = (s << 7) | (d & 127);
    }
}

// ---------------- MFMA GEMM: x = fp16(h) @ fp16(W), row-scaled by rsqrt(deg_out) in epilogue ----------------
#define A_LD 136
__global__ __launch_bounds__(256) void gemm_kernel(const float* __restrict__ hmat,
                                                   const float* __restrict__ W,
                                                   const int* __restrict__ deg_out,
                                                   __half* __restrict__ xh) {
    __shared__ _Float16 sA[64 * A_LD];
    __shared__ _Float16 sB[64 * A_LD];
    const int t = threadIdx.x;
    const int lane = t & 63;
    const int w = t >> 6;
    const int row0 = blockIdx.x * 64;
    const int m0 = (w & 1) * 32;
    const int n0 = (w >> 1) * 32;

    f32x4 acc00 = {0.f, 0.f, 0.f, 0.f}, acc01 = {0.f, 0.f, 0.f, 0.f};
    f32x4 acc10 = {0.f, 0.f, 0.f, 0.f}, acc11 = {0.f, 0.f, 0.f, 0.f};

    for (int khalf = 0; khalf < 2; ++khalf) {
        const int k0 = khalf * 128;
        __syncthreads();
#pragma unroll
        for (int it = 0; it < 8; ++it) {
            int f = t + it * 256;
            int row = f >> 5;
            int c4 = f & 31;
            int grow = row0 + row; if (grow >= N_NODES) grow = N_NODES - 1;
            float4 v = *(const float4*)(hmat + (size_t)grow * IN_DIM + k0 + c4 * 4);
            _Float16 p[4];
            p[0] = (_Float16)v.x; p[1] = (_Float16)v.y;
            p[2] = (_Float16)v.z; p[3] = (_Float16)v.w;
            *(uint2*)&sA[row * A_LD + c4 * 4] = *(uint2*)p;
        }
        {
            int n = t & 63;
            int kk0 = (t >> 6) * 32;
#pragma unroll
            for (int kb = 0; kb < 8; ++kb) {
                _Float16 p[4];
#pragma unroll
                for (int u = 0; u < 4; ++u)
                    p[u] = (_Float16)W[(size_t)(k0 + kk0 + kb * 4 + u) * OUT_DIM + n];
                *(uint2*)&sB[n * A_LD + kk0 + kb * 4] = *(uint2*)p;
            }
        }
        __syncthreads();
#pragma unroll
        for (int kb = 0; kb < 4; ++kb) {
            int koff = kb * 32 + (lane >> 4) * 8;
            half8 a0 = *(const half8*)&sA[(m0 + (lane & 15)) * A_LD + koff];
            half8 a1 = *(const half8*)&sA[(m0 + 16 + (lane & 15)) * A_LD + koff];
            half8 b0 = *(const half8*)&sB[(n0 + (lane & 15)) * A_LD + koff];
            half8 b1 = *(const half8*)&sB[(n0 + 16 + (lane & 15)) * A_LD + koff];
            acc00 = __builtin_amdgcn_mfma_f32_16x16x32_f16(a0, b0, acc00, 0, 0, 0);
            acc01 = __builtin_amdgcn_mfma_f32_16x16x32_f16(a0, b1, acc01, 0, 0, 0);
            acc10 = __builtin_amdgcn_mfma_f32_16x16x32_f16(a1, b0, acc10, 0, 0, 0);
            acc11 = __builtin_amdgcn_mfma_f32_16x16x32_f16(a1, b1, acc11, 0, 0, 0);
        }
    }

    const int col16 = lane & 15;
    const int rq = (lane >> 4) * 4;
#pragma unroll
    for (int mi = 0; mi < 2; ++mi) {
        float nrm[4];
#pragma unroll
        for (int r = 0; r < 4; ++r) {
            int row = row0 + m0 + mi * 16 + rq + r;
            int d = (row < N_NODES) ? deg_out[row] : 1;
            nrm[r] = rsqrtf((float)(d < 1 ? 1 : d));
        }
#pragma unroll
        for (int ni = 0; ni < 2; ++ni) {
            const f32x4 a = (mi == 0) ? (ni == 0 ? acc00 : acc01)
                                      : (ni == 0 ? acc10 : acc11);
            int col = n0 + ni * 16 + col16;
#pragma unroll
            for (int r = 0; r < 4; ++r) {
                int row = row0 + m0 + mi * 16 + rq + r;
                if (row < N_NODES)
                    xh[(size_t)row * OUT_DIM + col] = __float2half(a[r] * nrm[r]);
            }
        }
    }
}

// ---------------- pass 5: bin-level aggregation straight from binnedD ----------------
// One block per 128-node dst bin. acc[128][65] fp32 in LDS (65-pad rotates rows across
// banks so concurrent edges' ds_add_f32 spread: per-op an edge's 8 lanes hit 4 banks
// 2-way (free, m136); row phase = d mod 32). 8 lanes x uint4 per edge = one 128B row
// per 8-lane group, no dummy loads, deg_in histogrammed for free.
#define AGG_LD 65
__global__ __launch_bounds__(256) void aggregate_kernel(const int* __restrict__ CD,
                                                        const int* __restrict__ BS,
                                                        const int* __restrict__ binnedD,
                                                        const __half* __restrict__ xh,
                                                        const float* __restrict__ b,
                                                        float* __restrict__ out, int E) {
    __shared__ float acc[128 * AGG_LD];   // 33280 B
    __shared__ int cnt[128];
    __shared__ int sBS[64];
    const int t = threadIdx.x, bin = blockIdx.x;
    if (t < 64) {
        int v = (t < SB) ? BS[t] : 0;
        int incl = v;
#pragma unroll
        for (int off = 1; off < 64; off <<= 1) {
            int y = __shfl_up(incl, off);
            if (t >= off) incl += y;
        }
        sBS[t] = incl - v;
    }
    for (int i = t; i < 128 * AGG_LD; i += 256) acc[i] = 0.f;
    if (t < 128) cnt[t] = 0;
    __syncthreads();

    const int i0 = bin * NB;
    const int base = CD[i0] + sBS[i0 >> 12];
    const int next = (bin + 1 < NT) ? (CD[i0 + NB] + sBS[(i0 + NB) >> 12]) : E;

    const int c = t & 7;        // 16B column block within the 128B row
    const int eo = t >> 3;      // 32 edge slots per block iteration
    for (int k0 = base; k0 < next; k0 += 32 * 4) {
        int recs[4]; uint4 v[4];
#pragma unroll
        for (int u = 0; u < 4; ++u) {
            int k = k0 + u * 32 + eo;
            recs[u] = (k < next) ? binnedD[k] : -1;
        }
#pragma unroll
        for (int u = 0; u < 4; ++u) {
            int s = (recs[u] >= 0) ? (recs[u] >> 7) : 0;
            v[u] = *(const uint4*)(xh + (size_t)s * OUT_DIM + c * 8);
        }
#pragma unroll
        for (int u = 0; u < 4; ++u) {
            if (recs[u] >= 0) {
                int d = recs[u] & 127;
                float* row = &acc[d * AGG_LD + c * 8];
                const __half2* hp = (const __half2*)&v[u];
#pragma unroll
                for (int p = 0; p < 4; ++p) {
                    float2 f = __half22float2(hp[p]);
                    atomicAdd(row + 2 * p,     f.x);
                    atomicAdd(row + 2 * p + 1, f.y);
                }
                if (c == 0) atomicAdd(&cnt[d], 1);
            }
        }
    }
    __syncthreads();

    // epilogue: out = relu(acc * rsqrt(max(deg_in,1)) + b), coalesced float4 writes
    const int node0 = bin * 128;
#pragma unroll
    for (int i = t; i < 128 * 16; i += 256) {
        int r = i >> 4, q = i & 15;
        int node = node0 + r;
        if (node < N_NODES) {
            int n = cnt[r];
            float nrm = rsqrtf((float)(n < 1 ? 1 : n));
            const float* a = &acc[r * AGG_LD + q * 4];
            float4 bv = *(const float4*)(b + q * 4);
            float4 o;
            o.x = fmaxf(fmaf(a[0], nrm, bv.x), 0.f);
            o.y = fmaxf(fmaf(a[1], nrm, bv.y), 0.f);
            o.z = fmaxf(fmaf(a[2], nrm, bv.z), 0.f);
            o.w = fmaxf(fmaf(a[3], nrm, bv.w), 0.f);
            *(float4*)(out + (size_t)node * OUT_DIM + q * 4) = o;
        }
    }
}

extern "C" void kernel_launch(void* const* d_in, const int* in_sizes, int n_in,
                              void* d_out, int out_size, void* d_ws, size_t ws_size,
                              hipStream_t stream) {
    const float* h   = (const float*)d_in[0];
    const int*   src = (const int*)d_in[1];
    const int*   dst = (const int*)d_in[2];
    const float* W   = (const float*)d_in[3];
    const float* b   = (const float*)d_in[4];
    float* out = (float*)d_out;
    const int E = in_sizes[1];
    const int chunk = (E + NB - 1) / NB;

    // workspace layout (16B aligned); everything written before read
    char* ws = (char*)d_ws;
    int*    CD      = (int*)(ws);                    // NT*NB ints (800,768 B)
    int*    BS      = (int*)(ws + 800768);           // SB ints (padded to 256 B)
    int*    binnedD = (int*)(ws + 801024);           // E ints (6.4 MB)
    int*    deg_out = (int*)(ws + 7201024);          // N ints (400 KB)
    __half* xh      = (__half*)(ws + 7601024);       // N*64 halfs (12.8 MB)

    count_kernel<<<NB, 256, 0, stream>>>(dst, CD, deg_out, E, chunk);
    scan_blocks_kernel<<<SB, 256, 0, stream>>>(CD, BS);
    scatter_kernel<<<NB, 256, 0, stream>>>(src, dst, CD, BS, binnedD, deg_out, E, chunk);
    gemm_kernel<<<(N_NODES + 63) / 64, 256, 0, stream>>>(h, W, deg_out, xh);
    aggregate_kernel<<<NT, 256, 0, stream>>>(CD, BS, binnedD, xh, b, out, E);
}

// Round 3
// 319.502 us; speedup vs baseline: 2.9565x; 2.9565x over previous
//
#include <hip/hip_runtime.h>
#include <hip/hip_fp16.h>

#define N_NODES 100000
#define IN_DIM 256
#define OUT_DIM 64
#define NT 782                 // dst tiles of 128 nodes
#define NB 256                 // binning blocks
#define SCHUNK 4096            // scan chunk: 256 threads * 16
#define SB ((NT * NB + SCHUNK - 1) / SCHUNK)   // 49 scan chunks
#define SCAN_M (NT * NB)       // 200192

typedef _Float16 half8 __attribute__((ext_vector_type(8)));
typedef float f32x4 __attribute__((ext_vector_type(4)));

// ---------------- pass 1: per-block LDS histogram of dst>>7; zero deg_out ----------------
__global__ __launch_bounds__(256) void count_kernel(const int* __restrict__ dst,
                                                    int* __restrict__ CD,
                                                    int* __restrict__ deg_out,
                                                    int E, int chunk) {
    __shared__ int hd[NT];
    const int t = threadIdx.x, blk = blockIdx.x;
    for (int i = t; i < NT; i += 256) hd[i] = 0;
    // zero deg_out (scatter_kernel atomically builds it next pass)
    for (int i = blk * 256 + t; i < N_NODES; i += NB * 256) deg_out[i] = 0;
    __syncthreads();
    const int lo = blk * chunk;
    int hi = lo + chunk; if (hi > E) hi = E;
    for (int i = lo + t; i < hi; i += 256)
        atomicAdd(&hd[dst[i] >> 7], 1);
    __syncthreads();
    for (int i = t; i < NT; i += 256)
        CD[i * NB + blk] = hd[i];
}

// ---------------- pass 2: chunk-local exclusive scan of CD (in place) + chunk totals ----------------
__global__ __launch_bounds__(256) void scan_blocks_kernel(int* __restrict__ CD, int* __restrict__ BS) {
    const int cid = blockIdx.x;
    const int t = threadIdx.x;
    const int base = cid * SCHUNK + t * 16;
    int pre[16];
    int s = 0;
#pragma unroll
    for (int r = 0; r < 16; ++r) {
        int v = (base + r < SCAN_M) ? CD[base + r] : 0;
        pre[r] = s; s += v;
    }
    const int lane = t & 63;
    int incl = s;
#pragma unroll
    for (int off = 1; off < 64; off <<= 1) {
        int y = __shfl_up(incl, off);
        if (lane >= off) incl += y;
    }
    int wave_excl = incl - s;
    __shared__ int wtot[4];
    if (lane == 63) wtot[t >> 6] = incl;
    __syncthreads();
    int woff = 0;
    for (int w = 0; w < (t >> 6); ++w) woff += wtot[w];
    int bexcl = woff + wave_excl;
#pragma unroll
    for (int r = 0; r < 16; ++r)
        if (base + r < SCAN_M) CD[base + r] = bexcl + pre[r];
    if (t == 0) BS[cid] = wtot[0] + wtot[1] + wtot[2] + wtot[3];
}

// ---------------- pass 3: deterministic scatter into dst-binned records + deg_out atomics ----------------
// record = (src << 7) | (dst & 127). The 49 chunk totals are scanned in-LDS by wave 0.
__global__ __launch_bounds__(256) void scatter_kernel(const int* __restrict__ src,
                                                      const int* __restrict__ dst,
                                                      const int* __restrict__ CD,
                                                      const int* __restrict__ BS,
                                                      int* __restrict__ binnedD,
                                                      int* __restrict__ deg_out,
                                                      int E, int chunk) {
    __shared__ int curD[NT];
    __shared__ int sBS[64];
    const int t = threadIdx.x, blk = blockIdx.x;
    if (t < 64) {
        int v = (t < SB) ? BS[t] : 0;
        int incl = v;
#pragma unroll
        for (int off = 1; off < 64; off <<= 1) {
            int y = __shfl_up(incl, off);
            if (t >= off) incl += y;
        }
        sBS[t] = incl - v;
    }
    __syncthreads();
    for (int i = t; i < NT; i += 256) {
        int idx = i * NB + blk;
        curD[i] = CD[idx] + sBS[idx >> 12];
    }
    __syncthreads();
    const int lo = blk * chunk;
    int hi = lo + chunk; if (hi > E) hi = E;
    for (int i = lo + t; i < hi; i += 256) {
        int s = src[i], d = dst[i];
        atomicAdd(&deg_out[s], 1);
        int p = atomicAdd(&curD[d >> 7], 1);
        binnedD[p] = (s << 7) | (d & 127);
    }
}

// ---------------- pass 4: per-bin CSR-ify (dst only; src phase deleted) ----------------
__global__ __launch_bounds__(256) void tile_kernel(const int* __restrict__ CD,
                                                   const int* __restrict__ BS,
                                                   const int* __restrict__ binnedD,
                                                   int* __restrict__ csr,
                                                   int* __restrict__ offs, int* __restrict__ cnt,
                                                   int E) {
    __shared__ int h[128], cur[128];
    __shared__ int sBS[64];
    __shared__ int w0tot;
    const int bin = blockIdx.x, t = threadIdx.x, lane = t & 63;
    if (t < 64) {
        int vv = (t < SB) ? BS[t] : 0;
        int incl0 = vv;
#pragma unroll
        for (int off = 1; off < 64; off <<= 1) {
            int y = __shfl_up(incl0, off);
            if (t >= off) incl0 += y;
        }
        sBS[t] = incl0 - vv;
    }
    if (t < 128) h[t] = 0;
    __syncthreads();

    const int i0 = bin * NB;
    const int base = CD[i0] + sBS[i0 >> 12];
    const int next = (bin + 1 < NT) ? (CD[i0 + NB] + sBS[(i0 + NB) >> 12]) : E;
    const int m = next - base;
    for (int k = t; k < m; k += 256) atomicAdd(&h[binnedD[base + k] & 127], 1);
    __syncthreads();
    int v = (t < 128) ? h[t] : 0;
    int incl = v;
#pragma unroll
    for (int off = 1; off < 64; off <<= 1) {
        int y = __shfl_up(incl, off);
        if (lane >= off) incl += y;
    }
    if (t == 63) w0tot = incl;
    __syncthreads();
    int excl = incl - v + ((t >= 64 && t < 128) ? w0tot : 0);
    if (t < 128) {
        cur[t] = excl;
        int node = bin * 128 + t;
        if (node < N_NODES) { offs[node] = base + excl; cnt[node] = v; }
    }
    __syncthreads();
    for (int k = t; k < m; k += 256) {
        int rec = binnedD[base + k];
        int p = atomicAdd(&cur[rec & 127], 1);
        csr[base + p] = rec >> 7;
    }
}

// ---------------- MFMA GEMM: x = fp16(h) @ fp16(W), row-scaled by rsqrt(deg_out) in epilogue ----------------
#define A_LD 136
__global__ __launch_bounds__(256) void gemm_kernel(const float* __restrict__ hmat,
                                                   const float* __restrict__ W,
                                                   const int* __restrict__ deg_out,
                                                   __half* __restrict__ xh) {
    __shared__ _Float16 sA[64 * A_LD];
    __shared__ _Float16 sB[64 * A_LD];
    const int t = threadIdx.x;
    const int lane = t & 63;
    const int w = t >> 6;
    const int row0 = blockIdx.x * 64;
    const int m0 = (w & 1) * 32;
    const int n0 = (w >> 1) * 32;

    f32x4 acc00 = {0.f, 0.f, 0.f, 0.f}, acc01 = {0.f, 0.f, 0.f, 0.f};
    f32x4 acc10 = {0.f, 0.f, 0.f, 0.f}, acc11 = {0.f, 0.f, 0.f, 0.f};

    for (int khalf = 0; khalf < 2; ++khalf) {
        const int k0 = khalf * 128;
        __syncthreads();
#pragma unroll
        for (int it = 0; it < 8; ++it) {
            int f = t + it * 256;
            int row = f >> 5;
            int c4 = f & 31;
            int grow = row0 + row; if (grow >= N_NODES) grow = N_NODES - 1;
            float4 v = *(const float4*)(hmat + (size_t)grow * IN_DIM + k0 + c4 * 4);
            _Float16 p[4];
            p[0] = (_Float16)v.x; p[1] = (_Float16)v.y;
            p[2] = (_Float16)v.z; p[3] = (_Float16)v.w;
            *(uint2*)&sA[row * A_LD + c4 * 4] = *(uint2*)p;
        }
        {
            int n = t & 63;
            int kk0 = (t >> 6) * 32;
#pragma unroll
            for (int kb = 0; kb < 8; ++kb) {
                _Float16 p[4];
#pragma unroll
                for (int u = 0; u < 4; ++u)
                    p[u] = (_Float16)W[(size_t)(k0 + kk0 + kb * 4 + u) * OUT_DIM + n];
                *(uint2*)&sB[n * A_LD + kk0 + kb * 4] = *(uint2*)p;
            }
        }
        __syncthreads();
#pragma unroll
        for (int kb = 0; kb < 4; ++kb) {
            int koff = kb * 32 + (lane >> 4) * 8;
            half8 a0 = *(const half8*)&sA[(m0 + (lane & 15)) * A_LD + koff];
            half8 a1 = *(const half8*)&sA[(m0 + 16 + (lane & 15)) * A_LD + koff];
            half8 b0 = *(const half8*)&sB[(n0 + (lane & 15)) * A_LD + koff];
            half8 b1 = *(const half8*)&sB[(n0 + 16 + (lane & 15)) * A_LD + koff];
            acc00 = __builtin_amdgcn_mfma_f32_16x16x32_f16(a0, b0, acc00, 0, 0, 0);
            acc01 = __builtin_amdgcn_mfma_f32_16x16x32_f16(a0, b1, acc01, 0, 0, 0);
            acc10 = __builtin_amdgcn_mfma_f32_16x16x32_f16(a1, b0, acc10, 0, 0, 0);
            acc11 = __builtin_amdgcn_mfma_f32_16x16x32_f16(a1, b1, acc11, 0, 0, 0);
        }
    }

    const int col16 = lane & 15;
    const int rq = (lane >> 4) * 4;
#pragma unroll
    for (int mi = 0; mi < 2; ++mi) {
        float nrm[4];
#pragma unroll
        for (int r = 0; r < 4; ++r) {
            int row = row0 + m0 + mi * 16 + rq + r;
            int d = (row < N_NODES) ? deg_out[row] : 1;
            nrm[r] = rsqrtf((float)(d < 1 ? 1 : d));
        }
#pragma unroll
        for (int ni = 0; ni < 2; ++ni) {
            const f32x4 a = (mi == 0) ? (ni == 0 ? acc00 : acc01)
                                      : (ni == 0 ? acc10 : acc11);
            int col = n0 + ni * 16 + col16;
#pragma unroll
            for (int r = 0; r < 4; ++r) {
                int row = row0 + m0 + mi * 16 + rq + r;
                if (row < N_NODES)
                    xh[(size_t)row * OUT_DIM + col] = __float2half(a[r] * nrm[r]);
            }
        }
    }
}

// ---------------- pass 6: aggregate — one wave per node, 8 lanes x 16B per edge row ----------------
// g = lane>>3 (edge group), c = lane&7 (16B col-block). Edges quantized to 16-slot
// batches (2 statically-indexed loads in flight); the second load is skipped by a
// wave-uniform branch when the batch is half-empty. Typical deg-16 node: 2 useful
// loads, 0 dummies (old version: 2 useful + 2 dummy).
__global__ __launch_bounds__(256) void aggregate_kernel(const int* __restrict__ offs,
                                                        const int* __restrict__ cnt,
                                                        const int* __restrict__ csr,
                                                        const __half* __restrict__ xh,
                                                        const float* __restrict__ b,
                                                        float* __restrict__ out) {
    const int t = threadIdx.x;
    const int lane = t & 63;
    const int wid = t >> 6;
    const int node = blockIdx.x * 4 + wid;          // 25000*4 == N_NODES exactly
    const int g = lane >> 3;
    const int c = lane & 7;

    const int start = offs[node];
    const int n = cnt[node];

    float acc[8] = {0.f, 0.f, 0.f, 0.f, 0.f, 0.f, 0.f, 0.f};
    for (int base = 0; base < n; base += 64) {
        int k = base + lane;
        int sidx = (k < n) ? csr[start + k] : 0;
        int m = n - base; if (m > 64) m = 64;
        for (int e0 = 0; e0 < m; e0 += 16) {
            int ea = e0 + g;                 // <= 55
            int eb = e0 + 8 + g;             // <= 63
            int sa = __shfl(sidx, ea);
            int sb = __shfl(sidx, eb);
            bool va = ea < m;
            bool vb = eb < m;
            float wa = va ? 1.f : 0.f;
            float wb = vb ? 1.f : 0.f;
            uint4 ra = *(const uint4*)(xh + (size_t)(va ? sa : 0) * OUT_DIM + 8 * c);
            const bool grpb = (e0 + 8) < m;  // wave-uniform
            uint4 rb;
            if (grpb)
                rb = *(const uint4*)(xh + (size_t)(vb ? sb : 0) * OUT_DIM + 8 * c);
            {
                const __half2* hp = (const __half2*)&ra;
#pragma unroll
                for (int p = 0; p < 4; ++p) {
                    float2 f = __half22float2(hp[p]);
                    acc[2 * p]     = fmaf(wa, f.x, acc[2 * p]);
                    acc[2 * p + 1] = fmaf(wa, f.y, acc[2 * p + 1]);
                }
            }
            if (grpb) {
                const __half2* hp = (const __half2*)&rb;
#pragma unroll
                for (int p = 0; p < 4; ++p) {
                    float2 f = __half22float2(hp[p]);
                    acc[2 * p]     = fmaf(wb, f.x, acc[2 * p]);
                    acc[2 * p + 1] = fmaf(wb, f.y, acc[2 * p + 1]);
                }
            }
        }
    }

    // reduce over the 8 edge groups (lanes c, c+8, ..., c+56)
#pragma unroll
    for (int off = 8; off < 64; off <<= 1) {
#pragma unroll
        for (int p = 0; p < 8; ++p)
            acc[p] += __shfl_xor(acc[p], off);
    }

    if (g == 0) {   // lanes 0..7 hold the full sums for cols c*8..c*8+7
        float nrm = rsqrtf((float)(n < 1 ? 1 : n));
        float4 bv0 = *(const float4*)&b[c * 8];
        float4 bv1 = *(const float4*)&b[c * 8 + 4];
        float4 r0, r1;
        r0.x = fmaxf(fmaf(acc[0], nrm, bv0.x), 0.f);
        r0.y = fmaxf(fmaf(acc[1], nrm, bv0.y), 0.f);
        r0.z = fmaxf(fmaf(acc[2], nrm, bv0.z), 0.f);
        r0.w = fmaxf(fmaf(acc[3], nrm, bv0.w), 0.f);
        r1.x = fmaxf(fmaf(acc[4], nrm, bv1.x), 0.f);
        r1.y = fmaxf(fmaf(acc[5], nrm, bv1.y), 0.f);
        r1.z = fmaxf(fmaf(acc[6], nrm, bv1.z), 0.f);
        r1.w = fmaxf(fmaf(acc[7], nrm, bv1.w), 0.f);
        float4* orow = (float4*)(out + (size_t)node * OUT_DIM + c * 8);
        orow[0] = r0;
        orow[1] = r1;
    }
}

extern "C" void kernel_launch(void* const* d_in, const int* in_sizes, int n_in,
                              void* d_out, int out_size, void* d_ws, size_t ws_size,
                              hipStream_t stream) {
    const float* h   = (const float*)d_in[0];
    const int*   src = (const int*)d_in[1];
    const int*   dst = (const int*)d_in[2];
    const float* W   = (const float*)d_in[3];
    const float* b   = (const float*)d_in[4];
    float* out = (float*)d_out;
    const int E = in_sizes[1];
    const int chunk = (E + NB - 1) / NB;

    // workspace layout (16B aligned); everything written before read
    char* ws = (char*)d_ws;
    int*    CD      = (int*)(ws);                    // NT*NB ints (800,768 B)
    int*    BS      = (int*)(ws + 800768);           // SB ints (padded to 256 B)
    int*    binnedD = (int*)(ws + 801024);           // E ints (6.4 MB)
    int*    csr     = (int*)(ws + 7201024);          // E ints (6.4 MB)
    int*    offs    = (int*)(ws + 13601024);         // N ints
    int*    cntA    = (int*)(ws + 14001024);         // N ints
    int*    deg_out = (int*)(ws + 14401024);         // N ints
    __half* xh      = (__half*)(ws + 14801024);      // N*64 halfs (12.8 MB)

    count_kernel<<<NB, 256, 0, stream>>>(dst, CD, deg_out, E, chunk);
    scan_blocks_kernel<<<SB, 256, 0, stream>>>(CD, BS);
    scatter_kernel<<<NB, 256, 0, stream>>>(src, dst, CD, BS, binnedD, deg_out, E, chunk);
    tile_kernel<<<NT, 256, 0, stream>>>(CD, BS, binnedD, csr, offs, cntA, E);
    gemm_kernel<<<(N_NODES + 63) / 64, 256, 0, stream>>>(h, W, deg_out, xh);
    aggregate_kernel<<<N_NODES / 4, 256, 0, stream>>>(offs, cntA, csr, xh, b, out);
}